// Round 2
// 363.777 us; speedup vs baseline: 1.1893x; 1.1893x over previous
//
#include <hip/hip_runtime.h>

// SeparableConv3D fused single-pass: x[8,3,32,256,256] fp32, depthwise K=5
// cross-correlation along W, H, T, zero 'same' padding.
//
// v3b: software-pipelined. Register-prefetch of slice t+2 is issued right
// after the (single) barrier of iteration t and drained into LDS just
// before the barrier of iteration t+1 -> HBM latency hides under a full
// iteration of compute. sx and sy are double-buffered so ONE
// __syncthreads per t-slice suffices (33 barriers vs 64).
//
// Hazards (single barrier proof):
//   stage2(t) reads sx[t&1]   : written iter t-1 pre-barrier(t-1)   OK
//   write sx[(t+1)&1] @ t     : last read stage2(t-1) pre-barrier    OK
//   stage2(t) writes sy[t&1]  : last read stage3(t-2); barrier(t-1)  OK
//   stage3(t) reads sy[t&1]   : written stage2(t) pre-barrier(t)     OK
//
// HBM traffic: ~217 MB read + 201 MB write -> ~66 us floor @6.3 TB/s.

#define N_  8
#define C_  3
#define T_  32
#define H_  256
#define W_  256
#define K_  5
#define HW_ (H_ * W_)

#define TH 16
#define TW 64
// sx logical: 20 rows x 68 cols = 1360 floats; padded to 1536 so that the
// strided staging loop (6 x 256 = 1536 slots) can write zeros harmlessly.
#define SX_PAD_FLOATS 1536
#define SY_ROWS   20
#define SY_STRIDE 17   // float4 per row; padded from 16 to break row-stride
                       // == 0 (mod 32 banks) on stage-3 5-row reads

// clang-native 4-float vector: __builtin_nontemporal_store rejects HIP's
// float4 class type but accepts ext_vector_type.
typedef float nfloat4 __attribute__((ext_vector_type(4)));

__global__ __launch_bounds__(256)
void sep3d_fused3(const float* __restrict__ x,
                  const float* __restrict__ w1,
                  const float* __restrict__ w2,
                  const float* __restrict__ w3,
                  float* __restrict__ out)
{
    __shared__ float4 sx4[2][SX_PAD_FLOATS / 4];      // 2 x 6144 B
    __shared__ float4 sy4[2][SY_ROWS * SY_STRIDE];    // 2 x 5440 B

    const int tid = threadIdx.x;
    const int nc  = blockIdx.z;          // n*C + c
    const int c   = nc % C_;
    const int h0  = blockIdx.y * TH;
    const int w0  = blockIdx.x * TW;

    const float* xnc = x   + (size_t)nc * (T_ * HW_);
    float*       onc = out + (size_t)nc * (T_ * HW_);

    float k1[K_], k2[K_], k3[K_];
#pragma unroll
    for (int k = 0; k < K_; ++k) {
        k1[k] = w1[c * K_ + k];
        k2[k] = w2[c * K_ + k];
        k3[k] = w3[c * K_ + k];
    }

    // ---- Precompute halo-load descriptors (t-invariant) ----
    int  s1_off[6];
    bool s1_ok[6];
#pragma unroll
    for (int j = 0; j < 6; ++j) {
        int i   = tid + j * 256;         // [0, 1536)
        int row = i / 68;
        int col = i - row * 68;
        int gh  = h0 + row - 2;
        int gw  = w0 + col - 2;
        s1_ok[j]  = (i < 1360) && ((unsigned)gh < H_) && ((unsigned)gw < W_);
        s1_off[j] = gh * W_ + gw;
    }

    // ---- Stage-3 (H-conv + store) constants ----
    const int row3 = tid >> 4;           // 0..15
    const int seg3 = tid & 15;           // 0..15
    float* gst = onc + (h0 + row3) * W_ + (w0 + 4 * seg3);

    // T-conv register ring: at start of iter t,
    // a0=partial out(t-2), a1=out(t-1), a2=out(t), a3=out(t+1). Init 0.
    float4 a0 = {0,0,0,0}, a1 = a0, a2 = a0, a3 = a0;

    // ---- Prologue: slice 0 -> sx[0]; issue prefetch of slice 1 ----
    float p[6];
    {
#pragma unroll
        for (int j = 0; j < 6; ++j) p[j] = s1_ok[j] ? xnc[s1_off[j]] : 0.0f;
        float* sx0 = (float*)sx4[0];
#pragma unroll
        for (int j = 0; j < 6; ++j) sx0[tid + j * 256] = p[j];
        const float* xt1 = xnc + (size_t)HW_;
#pragma unroll
        for (int j = 0; j < 6; ++j) p[j] = s1_ok[j] ? xt1[s1_off[j]] : 0.0f;
    }
    __syncthreads();

    for (int t = 0; t < T_; ++t) {
        const int cur = t & 1;
        float* sxc = (float*)sx4[cur];
        float* sxn = (float*)sx4[cur ^ 1];

        // Stage 2: W-conv from sx[cur], 4 outputs/task, 320 tasks
#pragma unroll
        for (int rep = 0; rep < 2; ++rep) {
            int task = tid + rep * 256;
            if (task < 320) {
                int seg = task & 15, row = task >> 4;
                const float4* pp = (const float4*)&sxc[row * 68 + 4 * seg];
                float4 aa = pp[0], bb = pp[1];
                float xv0 = aa.x, xv1 = aa.y, xv2 = aa.z, xv3 = aa.w;
                float xv4 = bb.x, xv5 = bb.y, xv6 = bb.z, xv7 = bb.w;
                float4 y;
                y.x = xv0*k1[0] + xv1*k1[1] + xv2*k1[2] + xv3*k1[3] + xv4*k1[4];
                y.y = xv1*k1[0] + xv2*k1[1] + xv3*k1[2] + xv4*k1[3] + xv5*k1[4];
                y.z = xv2*k1[0] + xv3*k1[1] + xv4*k1[2] + xv5*k1[3] + xv6*k1[4];
                y.w = xv3*k1[0] + xv4*k1[1] + xv5*k1[2] + xv6*k1[3] + xv7*k1[4];
                sy4[cur][row * SY_STRIDE + seg] = y;
            }
        }

        // Drain prefetched slice t+1 into sx[nxt] (vmcnt wait lands here,
        // ~1 full iteration after the loads were issued).
#pragma unroll
        for (int j = 0; j < 6; ++j) sxn[tid + j * 256] = p[j];

        __syncthreads();   // the ONLY barrier of the iteration

        // Issue prefetch of slice t+2 (consumed next iteration, pre-barrier).
        if (t + 2 < T_) {
            const float* xt = xnc + (size_t)(t + 2) * HW_;
#pragma unroll
            for (int j = 0; j < 6; ++j) p[j] = s1_ok[j] ? xt[s1_off[j]] : 0.0f;
        } else {
#pragma unroll
            for (int j = 0; j < 6; ++j) p[j] = 0.0f;
        }

        // Stage 3: H-conv -> z (registers)
        float4 z = {0,0,0,0};
#pragma unroll
        for (int k = 0; k < K_; ++k) {
            float4 r = sy4[cur][(row3 + k) * SY_STRIDE + seg3];
            z.x += r.x * k2[k];
            z.y += r.y * k2[k];
            z.z += r.z * k2[k];
            z.w += r.w * k2[k];
        }

        // Stage 4: T-conv register ring update
        nfloat4 done;
        done.x = a0.x + z.x * k3[4];
        done.y = a0.y + z.y * k3[4];
        done.z = a0.z + z.z * k3[4];
        done.w = a0.w + z.w * k3[4];
        if (t >= 2)
            __builtin_nontemporal_store(done, (nfloat4*)(gst + (size_t)(t - 2) * HW_));
        a0.x = a1.x + z.x * k3[3];  a0.y = a1.y + z.y * k3[3];
        a0.z = a1.z + z.z * k3[3];  a0.w = a1.w + z.w * k3[3];
        a1.x = a2.x + z.x * k3[2];  a1.y = a2.y + z.y * k3[2];
        a1.z = a2.z + z.z * k3[2];  a1.w = a2.w + z.w * k3[2];
        a2.x = a3.x + z.x * k3[1];  a2.y = a3.y + z.y * k3[1];
        a2.z = a3.z + z.z * k3[1];  a2.w = a3.w + z.w * k3[1];
        a3.x = z.x * k3[0];  a3.y = z.y * k3[0];
        a3.z = z.z * k3[0];  a3.w = z.w * k3[0];
    }

    // Epilogue: out(30) = a0, out(31) = a1 (z(32), z(33) are zero padding)
    nfloat4 e0, e1;
    e0.x = a0.x; e0.y = a0.y; e0.z = a0.z; e0.w = a0.w;
    e1.x = a1.x; e1.y = a1.y; e1.z = a1.z; e1.w = a1.w;
    __builtin_nontemporal_store(e0, (nfloat4*)(gst + (size_t)30 * HW_));
    __builtin_nontemporal_store(e1, (nfloat4*)(gst + (size_t)31 * HW_));
}

extern "C" void kernel_launch(void* const* d_in, const int* in_sizes, int n_in,
                              void* d_out, int out_size, void* d_ws, size_t ws_size,
                              hipStream_t stream)
{
    const float* x  = (const float*)d_in[0];
    const float* w1 = (const float*)d_in[1];
    const float* w2 = (const float*)d_in[2];
    const float* w3 = (const float*)d_in[3];
    float* out = (float*)d_out;

    dim3 grid(W_ / TW, H_ / TH, N_ * C_);   // 4 x 16 x 24 = 1536 blocks
    sep3d_fused3<<<grid, 256, 0, stream>>>(x, w1, w2, w3, out);
}